// Round 1
// baseline (319.745 us; speedup 1.0000x reference)
//
#include <hip/hip_runtime.h>
#include <math.h>

#define N_TOK   16384
#define K_TOT   (8 * N_TOK)      // 131072 reduction rows per batch
#define N_BATCH 4
#define BPB     128              // K1 blocks per batch
#define RPB     (K_TOT / BPB)    // 1024 contiguous rows per block
#define CHUNK   64               // rows per LDS chunk
#define NCH     (RPB / CHUNK)    // 16 chunks per block
#define PITCH_U 36               // uints per LDS row (72 bf16, 16B-aligned)
#define PART_U  (64 * PITCH_U)   // 2304 uints per part (Ah/Al/Vh/Vl)

typedef short short8 __attribute__((ext_vector_type(8)));
typedef float f32x4  __attribute__((ext_vector_type(4)));

union FragU { uint4 u; short8 s; };

// RNE round fp32 -> bf16 (top 16 bits)
__device__ __forceinline__ uint bf16_rne(float f, float* rounded) {
  uint u = __float_as_uint(f);
  uint r = u + 0x7FFFu + ((u >> 16) & 1u);
  *rounded = __uint_as_float(r & 0xFFFF0000u);
  return r >> 16;
}

// barrier WITHOUT vmcnt drain: only lgkmcnt(0) (LDS visibility), then s_barrier.
// 0xC07F = vmcnt(63 = no wait) | expcnt(7 = no wait) | lgkmcnt(0).
__device__ __forceinline__ void barrier_nodrain() {
  asm volatile("" ::: "memory");
  __builtin_amdgcn_s_waitcnt(0xC07F);
  __builtin_amdgcn_s_barrier();
  asm volatile("" ::: "memory");
}

// ---------------------------------------------------------------------------
// K1: kv partials via MFMA bf16 hi/lo split. grid = 512 x 512 thr (8 waves).
// STREAMING K-loop: depth-2 register pipeline (chunks t+1,t+2 in flight) +
// dual LDS chunk buffers + raw s_barrier with NO vmcnt drain -> global loads
// outstanding continuously (HBM duty cycle ~100%, vs ~40% with __syncthreads'
// mandatory vmcnt(0)). One barrier per chunk:
//   issue loads(t+2) | compute(t) from LDS[t&1] | write regs(t+1)->LDS[(t+1)&1]
//   | lgkm-drain + s_barrier.
// compute(t) reads and write(t+1) writes DIFFERENT buffers; cross-iteration
// hazards are covered by the single barrier.
// ---------------------------------------------------------------------------
__global__ __launch_bounds__(512, 2) void k1_mfma(
    const float* __restrict__ key, const float* __restrict__ val,
    float* __restrict__ part) {
  __shared__ uint lds[2][4 * PART_U];   // 72 KiB: 2 x [Ah | Al | Vh | Vl]

  int blk  = blockIdx.x;
  int b    = blk / BPB;
  int p    = blk % BPB;
  int t    = threadIdx.x;
  int wave = t >> 6;
  int lane = t & 63;

  // staging role: threads 0-255 -> key, 256-511 -> val; 4x4 block per thread
  int arr = t >> 8;                  // 0 = key, 1 = val
  int tt  = t & 255;
  int c0  = (tt & 15) * 4;           // 4 consecutive channels
  int r0  = (tt >> 4) * 4;           // 4 consecutive rows
  const float* src = arr ? val : key;
  size_t rowbase = (size_t)b * K_TOT + (size_t)p * RPB;
  uint sbase = arr * 2 * PART_U;     // key -> parts 0/1, val -> parts 2/3

  // compute role: wave -> (m-tile, 2 n-tiles); 16x16x32 bf16 MFMA
  int mt  = wave >> 1;               // 0..3
  int ntb = (wave & 1) * 2;          // 0 or 2
  int m16 = lane & 15;
  int ko  = lane >> 4;               // k-octet 0..3

  f32x4 acc[2] = {{0.f, 0.f, 0.f, 0.f}, {0.f, 0.f, 0.f, 0.f}};
  float4 ld[2][4];                   // depth-2 pipeline registers

  auto load_chunk = [&](int ch, int par) {
#pragma unroll
    for (int q = 0; q < 4; q++)
      ld[par][q] =
          *(const float4*)&src[(rowbase + (size_t)ch * CHUNK + r0 + q) * 64 + c0];
  };

  auto write_chunk = [&](int par) {   // ld[par] -> lds[par], transposed hi/lo
#pragma unroll
    for (int cc = 0; cc < 4; cc++) {
      uint h[4], l[4];
#pragma unroll
      for (int q = 0; q < 4; q++) {
        float f = (&ld[par][q].x)[cc];
        float hf;
        h[q] = bf16_rne(f, &hf);
        float dummy;
        l[q] = bf16_rne(f - hf, &dummy);
      }
      uint2 hp = make_uint2(h[0] | (h[1] << 16), h[2] | (h[3] << 16));
      uint2 lp = make_uint2(l[0] | (l[1] << 16), l[2] | (l[3] << 16));
      uint base = sbase + (uint)(c0 + cc) * PITCH_U + (uint)(r0 >> 1);
      *(uint2*)&lds[par][base]          = hp;
      *(uint2*)&lds[par][base + PART_U] = lp;
    }
  };

  auto compute = [&](int par) {
#pragma unroll
    for (int ks = 0; ks < 2; ks++) {
      uint ao = (uint)(mt * 16 + m16) * PITCH_U + ks * 16 + ko * 4;
      FragU Ah, Al;
      Ah.u = *(const uint4*)&lds[par][ao];
      Al.u = *(const uint4*)&lds[par][ao + PART_U];
#pragma unroll
      for (int nn = 0; nn < 2; nn++) {
        uint bo = 2 * PART_U + (uint)((ntb + nn) * 16 + m16) * PITCH_U +
                  ks * 16 + ko * 4;
        FragU Bh, Bl;
        Bh.u = *(const uint4*)&lds[par][bo];
        Bl.u = *(const uint4*)&lds[par][bo + PART_U];
        acc[nn] = __builtin_amdgcn_mfma_f32_16x16x32_bf16(Ah.s, Bh.s, acc[nn], 0, 0, 0);
        acc[nn] = __builtin_amdgcn_mfma_f32_16x16x32_bf16(Ah.s, Bl.s, acc[nn], 0, 0, 0);
        acc[nn] = __builtin_amdgcn_mfma_f32_16x16x32_bf16(Al.s, Bh.s, acc[nn], 0, 0, 0);
      }
    }
  };

  // prologue: chunks 0 and 1 in flight; chunk 0 into LDS[0]
  load_chunk(0, 0);
  load_chunk(1, 1);
  write_chunk(0);          // compiler auto-waits vmcnt(4) for ld[0]
  barrier_nodrain();

#pragma unroll
  for (int ch = 0; ch < NCH; ch++) {
    if (ch + 2 < NCH) load_chunk(ch + 2, ch & 1);  // regs of chunk ch reusable
    compute(ch & 1);
    if (ch + 1 < NCH) write_chunk((ch + 1) & 1);   // auto vmcnt wait, t+2 stays in flight
    barrier_nodrain();
  }

  // epilogue: D layout col=lane&15, row=(lane>>4)*4+reg [m89-verified]
  float* dst = part + (size_t)blk * 4096;
#pragma unroll
  for (int nn = 0; nn < 2; nn++) {
    int d = (ntb + nn) * 16 + m16;
#pragma unroll
    for (int r = 0; r < 4; r++) {
      int c = mt * 16 + ko * 4 + r;
      dst[c * 64 + d] = acc[nn][r];
    }
  }
}

// ---------------------------------------------------------------------------
// K2: reduce 128 partial tiles per batch -> kv[b][c][d].
// ---------------------------------------------------------------------------
__global__ __launch_bounds__(256, 4) void k2_reduce(
    const float* __restrict__ part, float* __restrict__ kv, int bpb) {
  int b  = blockIdx.x >> 6;
  int c  = blockIdx.x & 63;
  int p4 = threadIdx.x >> 6;
  int d  = threadIdx.x & 63;

  float s = 0.f;
  int iters = bpb >> 2;
  const float* src = part + (size_t)(b * bpb) * 4096 + c * 64 + d;
#pragma unroll 4
  for (int x = 0; x < iters; x++) s += src[(size_t)(p4 + 4 * x) * 4096];

  __shared__ float l[256];
  l[threadIdx.x] = s;
  __syncthreads();
  if (p4 == 0)
    kv[((size_t)b * 64 + c) * 64 + d] = l[d] + l[64 + d] + l[128 + d] + l[192 + d];
}

// ---------------------------------------------------------------------------
// K2b: softmax over C (axis=1) -> P[b][c][d]. grid = 256 blocks (b,d),
// 64 threads = c; butterfly shuffle reductions.
// ---------------------------------------------------------------------------
__global__ __launch_bounds__(64, 4) void k2b_softmax(
    const float* __restrict__ kv, float* __restrict__ P) {
  int b = blockIdx.x >> 6;
  int d = blockIdx.x & 63;
  int c = threadIdx.x;
  float v = kv[(size_t)b * 4096 + c * 64 + d];
  float mx = v;
#pragma unroll
  for (int o = 32; o; o >>= 1) mx = fmaxf(mx, __shfl_xor(mx, o, 64));
  float e = __expf(v - mx);
  float s = e;
#pragma unroll
  for (int o = 32; o; o >>= 1) s += __shfl_xor(s, o, 64);
  P[(size_t)b * 4096 + c * 64 + d] = e / s;
}

// ---------------------------------------------------------------------------
// K3: out[b,m,d] = alpha * sum_c key_cur[b,m,c]*P[c,d] + val_cur[b,m,d].
// ---------------------------------------------------------------------------
__global__ __launch_bounds__(256, 4) void k3_out(
    const float* __restrict__ P, const float* __restrict__ keyc,
    const float* __restrict__ valc, const float* __restrict__ alphap,
    float* __restrict__ out) {
  __shared__ float Ps[4096];
  __shared__ float kT[64 * 68];

  int bb = blockIdx.x >> 8;
  int mb = blockIdx.x & 255;
  int m0 = mb * 64;
  int t = threadIdx.x;

  const float4* p4 = (const float4*)(P + (size_t)bb * 4096);
  float4* ps4 = (float4*)Ps;
#pragma unroll
  for (int u = 0; u < 4; u++) ps4[t + 256 * u] = p4[t + 256 * u];

  int r  = t >> 2;
  int cb = (t & 3) * 16;
  const float* krow = keyc + ((size_t)bb * N_TOK + m0 + r) * 64;
#pragma unroll
  for (int u = 0; u < 4; u++) {
    float4 kk = *(const float4*)&krow[cb + 4 * u];
    int c = cb + 4 * u;
    kT[(c + 0) * 68 + r] = kk.x;
    kT[(c + 1) * 68 + r] = kk.y;
    kT[(c + 2) * 68 + r] = kk.z;
    kT[(c + 3) * 68 + r] = kk.w;
  }
  __syncthreads();

  int wave = t >> 6, lane = t & 63;
  int mi = lane >> 3, j = lane & 7;
  int m = wave * 16 + mi * 2;

  float acc[2][8];
#pragma unroll
  for (int a = 0; a < 2; a++)
#pragma unroll
    for (int d = 0; d < 8; d++) acc[a][d] = 0.f;

#pragma unroll 4
  for (int c = 0; c < 64; c++) {
    float2 kk = *(const float2*)&kT[c * 68 + m];
    float4 p0 = *(const float4*)&Ps[c * 64 + 8 * j];
    float4 p1 = *(const float4*)&Ps[c * 64 + 8 * j + 4];
    float pr[8] = {p0.x, p0.y, p0.z, p0.w, p1.x, p1.y, p1.z, p1.w};
#pragma unroll
    for (int d = 0; d < 8; d++) {
      acc[0][d] = fmaf(kk.x, pr[d], acc[0][d]);
      acc[1][d] = fmaf(kk.y, pr[d], acc[1][d]);
    }
  }

  float alpha = alphap[0];
#pragma unroll
  for (int a = 0; a < 2; a++) {
    size_t off = ((size_t)bb * N_TOK + m0 + m + a) * 64 + 8 * j;
    float4 v0 = *(const float4*)&valc[off];
    float4 v1 = *(const float4*)&valc[off + 4];
    float4 o0 = make_float4(fmaf(alpha, acc[a][0], v0.x),
                            fmaf(alpha, acc[a][1], v0.y),
                            fmaf(alpha, acc[a][2], v0.z),
                            fmaf(alpha, acc[a][3], v0.w));
    float4 o1 = make_float4(fmaf(alpha, acc[a][4], v1.x),
                            fmaf(alpha, acc[a][5], v1.y),
                            fmaf(alpha, acc[a][6], v1.z),
                            fmaf(alpha, acc[a][7], v1.w));
    *(float4*)&out[off] = o0;
    *(float4*)&out[off + 4] = o1;
  }
}

// ---------------------------------------------------------------------------
extern "C" void kernel_launch(void* const* d_in, const int* in_sizes, int n_in,
                              void* d_out, int out_size, void* d_ws,
                              size_t ws_size, hipStream_t stream) {
  const float* key_mem = (const float*)d_in[0];
  const float* val_mem = (const float*)d_in[1];
  const float* key_cur = (const float*)d_in[2];
  const float* val_cur = (const float*)d_in[3];
  const float* alpha   = (const float*)d_in[4];
  float* out = (float*)d_out;
  float* ws  = (float*)d_ws;

  float* part = ws;                                    // 512 tiles (8.4 MB)
  float* kv   = ws + (size_t)(N_BATCH * BPB) * 4096;   // 4 tiles
  float* P    = ws;                                    // aliases consumed part

  k1_mfma<<<N_BATCH * BPB, 512, 0, stream>>>(key_mem, val_mem, part);
  k2_reduce<<<256, 256, 0, stream>>>(part, kv, BPB);
  k2b_softmax<<<N_BATCH * 64, 64, 0, stream>>>(kv, P);
  k3_out<<<N_BATCH * (N_TOK / 64), 256, 0, stream>>>(P, key_cur, val_cur,
                                                     alpha, out);
}

// Round 2
// 314.869 us; speedup vs baseline: 1.0155x; 1.0155x over previous
//
#include <hip/hip_runtime.h>
#include <math.h>

#define N_TOK   16384
#define K_TOT   (8 * N_TOK)      // 131072 reduction rows per batch
#define N_BATCH 4
#define BPB     128              // K1 blocks per batch
#define RPB     (K_TOT / BPB)    // 1024 contiguous rows per block
#define CHUNK   64               // rows per LDS chunk
#define NCH     (RPB / CHUNK)    // 16 chunks per block
// PITCH_U = 34: 4*34 = 136 = 8 (mod 32) -> staging uint2 writes hit
// 16 distinct banks x 4 lanes (conflict-free minimum); rows are 8B-aligned
// so fragment loads use 2x ds_read_b64 (also conflict-free: 2*m16+4*ko
// covers all 16 even residues). Old PITCH_U=36 gave 8-way write conflicts
// (1.78e7 conflict cycles = 28% of k1).
#define PITCH_U 34               // uints per LDS row (64 bf16 data + 2 pad)
#define PART_U  (64 * PITCH_U)   // 2176 uints per part (Ah/Al/Vh/Vl)

typedef short short8 __attribute__((ext_vector_type(8)));
typedef float f32x4  __attribute__((ext_vector_type(4)));

union FragU { uint4 u; short8 s; };

// RNE round fp32 -> bf16 (top 16 bits)
__device__ __forceinline__ uint bf16_rne(float f, float* rounded) {
  uint u = __float_as_uint(f);
  uint r = u + 0x7FFFu + ((u >> 16) & 1u);
  *rounded = __uint_as_float(r & 0xFFFF0000u);
  return r >> 16;
}

// barrier WITHOUT vmcnt drain: only lgkmcnt(0) (LDS visibility), then s_barrier.
// 0xC07F = vmcnt(63 = no wait) | expcnt(7 = no wait) | lgkmcnt(0).
__device__ __forceinline__ void barrier_nodrain() {
  asm volatile("" ::: "memory");
  __builtin_amdgcn_s_waitcnt(0xC07F);
  __builtin_amdgcn_s_barrier();
  asm volatile("" ::: "memory");
}

// ---------------------------------------------------------------------------
// K1: kv partials via MFMA bf16 hi/lo split. grid = 512 x 512 thr (8 waves).
// STREAMING K-loop: depth-2 register pipeline + dual LDS chunk buffers + raw
// s_barrier with NO vmcnt drain -> global loads outstanding continuously.
// One barrier per chunk:
//   issue loads(t+2) | compute(t) from LDS[t&1] | write regs(t+1)->LDS[(t+1)&1]
//   | lgkm-drain + s_barrier.
// ---------------------------------------------------------------------------
__global__ __launch_bounds__(512, 2) void k1_mfma(
    const float* __restrict__ key, const float* __restrict__ val,
    float* __restrict__ part) {
  __shared__ uint lds[2][4 * PART_U];   // 68 KiB: 2 x [Ah | Al | Vh | Vl]

  int blk  = blockIdx.x;
  int b    = blk / BPB;
  int p    = blk % BPB;
  int t    = threadIdx.x;
  int wave = t >> 6;
  int lane = t & 63;

  // staging role: threads 0-255 -> key, 256-511 -> val; 4x4 block per thread
  int arr = t >> 8;                  // 0 = key, 1 = val
  int tt  = t & 255;
  int c0  = (tt & 15) * 4;           // 4 consecutive channels
  int r0  = (tt >> 4) * 4;           // 4 consecutive rows
  const float* src = arr ? val : key;
  size_t rowbase = (size_t)b * K_TOT + (size_t)p * RPB;
  uint sbase = arr * 2 * PART_U;     // key -> parts 0/1, val -> parts 2/3

  // compute role: wave -> (m-tile, 2 n-tiles); 16x16x32 bf16 MFMA
  int mt  = wave >> 1;               // 0..3
  int ntb = (wave & 1) * 2;          // 0 or 2
  int m16 = lane & 15;
  int ko  = lane >> 4;               // k-octet 0..3

  f32x4 acc[2] = {{0.f, 0.f, 0.f, 0.f}, {0.f, 0.f, 0.f, 0.f}};
  float4 ld[2][4];                   // depth-2 pipeline registers

  auto load_chunk = [&](int ch, int par) {
#pragma unroll
    for (int q = 0; q < 4; q++)
      ld[par][q] =
          *(const float4*)&src[(rowbase + (size_t)ch * CHUNK + r0 + q) * 64 + c0];
  };

  auto write_chunk = [&](int par) {   // ld[par] -> lds[par], transposed hi/lo
#pragma unroll
    for (int cc = 0; cc < 4; cc++) {
      uint h[4], l[4];
#pragma unroll
      for (int q = 0; q < 4; q++) {
        float f = (&ld[par][q].x)[cc];
        float hf;
        h[q] = bf16_rne(f, &hf);
        float dummy;
        l[q] = bf16_rne(f - hf, &dummy);
      }
      uint2 hp = make_uint2(h[0] | (h[1] << 16), h[2] | (h[3] << 16));
      uint2 lp = make_uint2(l[0] | (l[1] << 16), l[2] | (l[3] << 16));
      uint base = sbase + (uint)(c0 + cc) * PITCH_U + (uint)(r0 >> 1);
      *(uint2*)&lds[par][base]          = hp;
      *(uint2*)&lds[par][base + PART_U] = lp;
    }
  };

  // fragment load: two 8B LDS reads (rows only 8B-aligned with PITCH_U=34)
  auto frag = [&](uint idx) {
    FragU F;
    uint2 a0 = *(const uint2*)&lds[0][0];  // placeholder (overwritten below)
    (void)a0;
    uint2 lo = *(const uint2*)&((&lds[0][0])[idx]);
    uint2 hi = *(const uint2*)&((&lds[0][0])[idx + 2]);
    F.u = make_uint4(lo.x, lo.y, hi.x, hi.y);
    return F;
  };

  auto compute = [&](int par) {
    const uint* L = &lds[par][0];
#pragma unroll
    for (int ks = 0; ks < 2; ks++) {
      uint ao = (uint)(mt * 16 + m16) * PITCH_U + ks * 16 + ko * 4;
      FragU Ah, Al;
      {
        uint2 lo = *(const uint2*)&L[ao];
        uint2 hi = *(const uint2*)&L[ao + 2];
        Ah.u = make_uint4(lo.x, lo.y, hi.x, hi.y);
      }
      {
        uint2 lo = *(const uint2*)&L[ao + PART_U];
        uint2 hi = *(const uint2*)&L[ao + PART_U + 2];
        Al.u = make_uint4(lo.x, lo.y, hi.x, hi.y);
      }
#pragma unroll
      for (int nn = 0; nn < 2; nn++) {
        uint bo = 2 * PART_U + (uint)((ntb + nn) * 16 + m16) * PITCH_U +
                  ks * 16 + ko * 4;
        FragU Bh, Bl;
        {
          uint2 lo = *(const uint2*)&L[bo];
          uint2 hi = *(const uint2*)&L[bo + 2];
          Bh.u = make_uint4(lo.x, lo.y, hi.x, hi.y);
        }
        {
          uint2 lo = *(const uint2*)&L[bo + PART_U];
          uint2 hi = *(const uint2*)&L[bo + PART_U + 2];
          Bl.u = make_uint4(lo.x, lo.y, hi.x, hi.y);
        }
        acc[nn] = __builtin_amdgcn_mfma_f32_16x16x32_bf16(Ah.s, Bh.s, acc[nn], 0, 0, 0);
        acc[nn] = __builtin_amdgcn_mfma_f32_16x16x32_bf16(Ah.s, Bl.s, acc[nn], 0, 0, 0);
        acc[nn] = __builtin_amdgcn_mfma_f32_16x16x32_bf16(Al.s, Bh.s, acc[nn], 0, 0, 0);
      }
    }
  };

  // prologue: chunks 0 and 1 in flight; chunk 0 into LDS[0]
  load_chunk(0, 0);
  load_chunk(1, 1);
  write_chunk(0);          // compiler auto-waits vmcnt(4) for ld[0]
  barrier_nodrain();

#pragma unroll
  for (int ch = 0; ch < NCH; ch++) {
    if (ch + 2 < NCH) load_chunk(ch + 2, ch & 1);  // regs of chunk ch reusable
    compute(ch & 1);
    if (ch + 1 < NCH) write_chunk((ch + 1) & 1);   // auto vmcnt wait, t+2 stays in flight
    barrier_nodrain();
  }

  // epilogue: D layout col=lane&15, row=(lane>>4)*4+reg [m89-verified]
  float* dst = part + (size_t)blk * 4096;
#pragma unroll
  for (int nn = 0; nn < 2; nn++) {
    int d = (ntb + nn) * 16 + m16;
#pragma unroll
    for (int r = 0; r < 4; r++) {
      int c = mt * 16 + ko * 4 + r;
      dst[c * 64 + d] = acc[nn][r];
    }
  }
}

// ---------------------------------------------------------------------------
// K2: reduce 128 partial tiles per batch -> kv[b][c][d].
// ---------------------------------------------------------------------------
__global__ __launch_bounds__(256, 4) void k2_reduce(
    const float* __restrict__ part, float* __restrict__ kv, int bpb) {
  int b  = blockIdx.x >> 6;
  int c  = blockIdx.x & 63;
  int p4 = threadIdx.x >> 6;
  int d  = threadIdx.x & 63;

  float s = 0.f;
  int iters = bpb >> 2;
  const float* src = part + (size_t)(b * bpb) * 4096 + c * 64 + d;
#pragma unroll 4
  for (int x = 0; x < iters; x++) s += src[(size_t)(p4 + 4 * x) * 4096];

  __shared__ float l[256];
  l[threadIdx.x] = s;
  __syncthreads();
  if (p4 == 0)
    kv[((size_t)b * 64 + c) * 64 + d] = l[d] + l[64 + d] + l[128 + d] + l[192 + d];
}

// ---------------------------------------------------------------------------
// K3: fused softmax + out.
//   e[c][d]   = exp(kv[b][c][d] - max_c kv[b][:,d])   (unnormalized)
//   out[b,m,d]= (alpha/den[d]) * sum_c key_cur[b,m,c]*e[c][d] + val_cur[b,m,d]
// Softmax normalization commutes with the c-contraction, so it folds into the
// epilogue scale -> k2b kernel deleted, one fewer launch + global round-trip.
// ---------------------------------------------------------------------------
__global__ __launch_bounds__(256, 4) void k3_out(
    const float* __restrict__ kv, const float* __restrict__ keyc,
    const float* __restrict__ valc, const float* __restrict__ alphap,
    float* __restrict__ out) {
  __shared__ float Ps[4096];       // e = exp(kv - mx[d])
  __shared__ float kT[64 * 68];
  __shared__ float redm[4][64];    // per-group partial max over c
  __shared__ float reds[4][64];    // per-group partial sum of e over c

  int bb = blockIdx.x >> 8;
  int mb = blockIdx.x & 255;
  int m0 = mb * 64;
  int t = threadIdx.x;

  // softmax role: thread (cg, d) reduces c = cg*16 .. cg*16+15 of column d
  int d  = t & 63;
  int cg = t >> 6;
  const float* kvb = kv + (size_t)bb * 4096;
  float v[16];
  float mx = -3.0e38f;
#pragma unroll
  for (int i = 0; i < 16; i++) {
    v[i] = kvb[(cg * 16 + i) * 64 + d];
    mx = fmaxf(mx, v[i]);
  }
  redm[cg][d] = mx;

  // kT staging (independent of softmax; same barrier covers both)
  int r  = t >> 2;
  int cb = (t & 3) * 16;
  const float* krow = keyc + ((size_t)bb * N_TOK + m0 + r) * 64;
#pragma unroll
  for (int u = 0; u < 4; u++) {
    float4 kk = *(const float4*)&krow[cb + 4 * u];
    int c = cb + 4 * u;
    kT[(c + 0) * 68 + r] = kk.x;
    kT[(c + 1) * 68 + r] = kk.y;
    kT[(c + 2) * 68 + r] = kk.z;
    kT[(c + 3) * 68 + r] = kk.w;
  }
  __syncthreads();

  mx = fmaxf(fmaxf(redm[0][d], redm[1][d]), fmaxf(redm[2][d], redm[3][d]));
  float s = 0.f;
#pragma unroll
  for (int i = 0; i < 16; i++) {
    float e = __expf(v[i] - mx);
    Ps[(cg * 16 + i) * 64 + d] = e;
    s += e;
  }
  reds[cg][d] = s;
  __syncthreads();

  int wave = t >> 6, lane = t & 63;
  int mi = lane >> 3, j = lane & 7;
  int m = wave * 16 + mi * 2;

  float acc[2][8];
#pragma unroll
  for (int a = 0; a < 2; a++)
#pragma unroll
    for (int dd = 0; dd < 8; dd++) acc[a][dd] = 0.f;

#pragma unroll 4
  for (int c = 0; c < 64; c++) {
    float2 kk = *(const float2*)&kT[c * 68 + m];
    float4 p0 = *(const float4*)&Ps[c * 64 + 8 * j];
    float4 p1 = *(const float4*)&Ps[c * 64 + 8 * j + 4];
    float pr[8] = {p0.x, p0.y, p0.z, p0.w, p1.x, p1.y, p1.z, p1.w};
#pragma unroll
    for (int dd = 0; dd < 8; dd++) {
      acc[0][dd] = fmaf(kk.x, pr[dd], acc[0][dd]);
      acc[1][dd] = fmaf(kk.y, pr[dd], acc[1][dd]);
    }
  }

  float alpha = alphap[0];
  float sc[8];
#pragma unroll
  for (int dd = 0; dd < 8; dd++) {
    int dq = 8 * j + dd;
    float den = reds[0][dq] + reds[1][dq] + reds[2][dq] + reds[3][dq];
    sc[dd] = alpha / den;
  }

#pragma unroll
  for (int a = 0; a < 2; a++) {
    size_t off = ((size_t)bb * N_TOK + m0 + m + a) * 64 + 8 * j;
    float4 v0 = *(const float4*)&valc[off];
    float4 v1 = *(const float4*)&valc[off + 4];
    float4 o0 = make_float4(fmaf(sc[0], acc[a][0], v0.x),
                            fmaf(sc[1], acc[a][1], v0.y),
                            fmaf(sc[2], acc[a][2], v0.z),
                            fmaf(sc[3], acc[a][3], v0.w));
    float4 o1 = make_float4(fmaf(sc[4], acc[a][4], v1.x),
                            fmaf(sc[5], acc[a][5], v1.y),
                            fmaf(sc[6], acc[a][6], v1.z),
                            fmaf(sc[7], acc[a][7], v1.w));
    *(float4*)&out[off] = o0;
    *(float4*)&out[off + 4] = o1;
  }
}

// ---------------------------------------------------------------------------
extern "C" void kernel_launch(void* const* d_in, const int* in_sizes, int n_in,
                              void* d_out, int out_size, void* d_ws,
                              size_t ws_size, hipStream_t stream) {
  const float* key_mem = (const float*)d_in[0];
  const float* val_mem = (const float*)d_in[1];
  const float* key_cur = (const float*)d_in[2];
  const float* val_cur = (const float*)d_in[3];
  const float* alpha   = (const float*)d_in[4];
  float* out = (float*)d_out;
  float* ws  = (float*)d_ws;

  float* part = ws;                                    // 512 tiles (8.4 MB)
  float* kv   = ws + (size_t)(N_BATCH * BPB) * 4096;   // 4 tiles

  k1_mfma<<<N_BATCH * BPB, 512, 0, stream>>>(key_mem, val_mem, part);
  k2_reduce<<<256, 256, 0, stream>>>(part, kv, BPB);
  k3_out<<<N_BATCH * (N_TOK / 64), 256, 0, stream>>>(kv, key_cur, val_cur,
                                                     alpha, out);
}